// Round 3
// baseline (1257.669 us; speedup 1.0000x reference)
//
#include <hip/hip_runtime.h>
#include <cmath>

typedef __bf16 bf16;
typedef __bf16 bf16x8 __attribute__((ext_vector_type(8)));
typedef float f32x4 __attribute__((ext_vector_type(4)));

#define B_ 2
#define S_ 2048
#define D_ 1024
#define H_ 16
#define HD_ 64
#define MLP_ 4096
#define XOUT_ ((size_t)B_ * S_ * D_)   // 4194304 elements

__device__ __forceinline__ void gll16(const void* g, void* l) {
  __builtin_amdgcn_global_load_lds((const __attribute__((address_space(1))) void*)g,
                                   (__attribute__((address_space(3))) void*)l, 16, 0, 0);
}

__device__ __forceinline__ f32x4 mfma16(bf16x8 a, bf16x8 b, f32x4 c) {
  return __builtin_amdgcn_mfma_f32_16x16x32_bf16(a, b, c, 0, 0, 0);
}

__device__ __forceinline__ float bfu2f(unsigned short u) {
  return __uint_as_float(((unsigned int)u) << 16);
}
__device__ __forceinline__ unsigned short f2bu(float v) {
  union { bf16 b; unsigned short u; } c; c.b = (bf16)v; return c.u;
}
__device__ __forceinline__ float ld_sc(const void* p, size_t i, int f32) {
  return f32 ? ((const float*)p)[i] : bfu2f(((const unsigned short*)p)[i]);
}

// ---------------- dtype detector ----------------
__global__ __launch_bounds__(64) void detect_k(const unsigned short* __restrict__ x,
                                               int* __restrict__ flag) {
  int tid = threadIdx.x;
  int cnt = 0;
  for (int i = tid; i < 512; i += 64) {
    int e = (x[i] >> 7) & 0xFF;
    if (e >= 0xBF) cnt++;
  }
  #pragma unroll
  for (int d = 1; d < 64; d <<= 1) cnt += __shfl_xor(cnt, d);
  if (tid == 0) flag[0] = (cnt > 8) ? 1 : 0;
}

// ---------------- adaptive transpose: in [R][C] -> out bf16 [C][R] ----------------
__global__ __launch_bounds__(256) void transpose_ad(const void* __restrict__ in,
                                                    unsigned short* __restrict__ out,
                                                    int R, int C,
                                                    const int* __restrict__ flagp) {
  __shared__ unsigned short t[64][68];
  const int f32 = flagp[0];
  const int tid = threadIdx.x;
  const int c0 = blockIdx.x * 64, r0 = blockIdx.y * 64;
  for (int i = tid * 4; i < 4096; i += 1024) {
    int rr = i >> 6, cc = i & 63;
    size_t off = (size_t)(r0 + rr) * C + c0 + cc;
    if (f32) {
      float4 f = *(const float4*)((const float*)in + off);
      t[rr][cc + 0] = f2bu(f.x); t[rr][cc + 1] = f2bu(f.y);
      t[rr][cc + 2] = f2bu(f.z); t[rr][cc + 3] = f2bu(f.w);
    } else {
      *(ushort4*)&t[rr][cc] = *(const ushort4*)((const unsigned short*)in + off);
    }
  }
  __syncthreads();
  for (int i = tid * 4; i < 4096; i += 1024) {
    int orr = i & 63, oc = i >> 6;
    ushort4 v;
    v.x = t[orr + 0][oc]; v.y = t[orr + 1][oc];
    v.z = t[orr + 2][oc]; v.w = t[orr + 3][oc];
    *(ushort4*)(out + (size_t)(c0 + oc) * R + r0 + orr) = v;
  }
}

// ---------------- V transpose: qkv v-part -> vT[b][h][hd][s] ----------------
__global__ __launch_bounds__(256) void vtrans_k(const unsigned short* __restrict__ qkv,
                                                unsigned short* __restrict__ vT) {
  __shared__ unsigned short t[64][68];
  const int tid = threadIdx.x;
  const int s0 = blockIdx.x * 64, h = blockIdx.y, b = blockIdx.z;
  for (int i = tid * 4; i < 4096; i += 1024) {
    int si = i >> 6, hd = i & 63;
    *(ushort4*)&t[si][hd] =
        *(const ushort4*)(qkv + (size_t)(b * S_ + s0 + si) * 3072 + 2048 + h * 64 + hd);
  }
  __syncthreads();
  for (int i = tid * 4; i < 4096; i += 1024) {
    int ss = i & 63, hd = i >> 6;
    ushort4 v;
    v.x = t[ss + 0][hd]; v.y = t[ss + 1][hd];
    v.z = t[ss + 2][hd]; v.w = t[ss + 3][hd];
    *(ushort4*)(vT + ((size_t)(b * H_ + h) * 64 + hd) * S_ + s0 + ss) = v;
  }
}

// ---------------- LayerNorm ----------------
__global__ __launch_bounds__(256) void ln_k(const void* __restrict__ xv,
                                            const void* __restrict__ g,
                                            const void* __restrict__ bvec,
                                            bf16* __restrict__ out,
                                            const int* __restrict__ flagp,
                                            int force_xf32) {
  const int f32 = flagp[0];
  const int xf32 = force_xf32 ? 1 : f32;
  const int row = blockIdx.x, tid = threadIdx.x;
  float v[4];
  if (xf32) {
    float4 f = *(const float4*)((const float*)xv + (size_t)row * 1024 + tid * 4);
    v[0] = f.x; v[1] = f.y; v[2] = f.z; v[3] = f.w;
  } else {
    ushort4 u = *(const ushort4*)((const unsigned short*)xv + (size_t)row * 1024 + tid * 4);
    v[0] = bfu2f(u.x); v[1] = bfu2f(u.y); v[2] = bfu2f(u.z); v[3] = bfu2f(u.w);
  }
  float s = 0.f, q = 0.f;
  #pragma unroll
  for (int i = 0; i < 4; i++) { s += v[i]; q += v[i] * v[i]; }
  #pragma unroll
  for (int d = 1; d < 64; d <<= 1) { s += __shfl_xor(s, d); q += __shfl_xor(q, d); }
  __shared__ float red[8];
  if ((tid & 63) == 0) { red[(tid >> 6) * 2] = s; red[(tid >> 6) * 2 + 1] = q; }
  __syncthreads();
  s = red[0] + red[2] + red[4] + red[6];
  q = red[1] + red[3] + red[5] + red[7];
  const float mean = s * (1.0f / 1024.0f);
  const float var = q * (1.0f / 1024.0f) - mean * mean;
  const float rs = rsqrtf(var + 1e-5f);
  unsigned short ov[4];
  #pragma unroll
  for (int i = 0; i < 4; i++) {
    float gg = ld_sc(g, tid * 4 + i, f32);
    float bb = ld_sc(bvec, tid * 4 + i, f32);
    ov[i] = f2bu((v[i] - mean) * rs * gg + bb);
  }
  ushort4 o4; o4.x = ov[0]; o4.y = ov[1]; o4.z = ov[2]; o4.w = ov[3];
  *(ushort4*)((unsigned short*)out + (size_t)row * 1024 + tid * 4) = o4;
}

// ---------------- GEMM 128x128 (BK=64): C = A * BT^T ----------------
// MODE 0: bf16 = acc; MODE 1: bf16 = gelu(acc+bias);
// MODE 2: f32 = acc + res(adaptive); MODE 3: (bf16|f32) = acc + bias + resf
template <int MODE>
__global__ __launch_bounds__(256) void gemm_bt(const bf16* __restrict__ A,
                                               const bf16* __restrict__ BT,
                                               int N, int K,
                                               const void* __restrict__ bias,
                                               const void* __restrict__ resb,
                                               const float* __restrict__ resf,
                                               bf16* __restrict__ outb,
                                               float* __restrict__ outf,
                                               const int* __restrict__ flagp) {
  __shared__ __align__(16) bf16 sA[128 * 64];
  __shared__ __align__(16) bf16 sB[128 * 64];
  const int f32 = flagp[0];
  const int tid = threadIdx.x;
  const int lane = tid & 63;
  const int wave = tid >> 6;
  const int wm = wave >> 1, wn = wave & 1;
  const int m0 = blockIdx.y * 128, n0 = blockIdx.x * 128;
  const int cn = lane & 15, rl = lane >> 4;
  const int r0 = tid >> 3, c16 = tid & 7;

  f32x4 zero = {0.f, 0.f, 0.f, 0.f};
  f32x4 acc[4][4];
  #pragma unroll
  for (int i = 0; i < 4; i++)
    #pragma unroll
    for (int j = 0; j < 4; j++) acc[i][j] = zero;

  for (int k0 = 0; k0 < K; k0 += 64) {
    __syncthreads();
    #pragma unroll
    for (int i = 0; i < 4; i++) {
      int row = r0 + i * 32;
      gll16(A + (size_t)(m0 + row) * K + k0 + c16 * 8, &sA[row * 64 + c16 * 8]);
      gll16(BT + (size_t)(n0 + row) * K + k0 + c16 * 8, &sB[row * 64 + c16 * 8]);
    }
    __syncthreads();
    #pragma unroll
    for (int kk = 0; kk < 64; kk += 32) {
      bf16x8 af[4], bfr[4];
      #pragma unroll
      for (int t = 0; t < 4; t++) {
        af[t] = *(const bf16x8*)&sA[(wm * 64 + t * 16 + cn) * 64 + kk + rl * 8];
        bfr[t] = *(const bf16x8*)&sB[(wn * 64 + t * 16 + cn) * 64 + kk + rl * 8];
      }
      #pragma unroll
      for (int mt = 0; mt < 4; mt++)
        #pragma unroll
        for (int nt = 0; nt < 4; nt++)
          acc[mt][nt] = mfma16(af[mt], bfr[nt], acc[mt][nt]);
    }
  }

  #pragma unroll
  for (int mt = 0; mt < 4; mt++)
    #pragma unroll
    for (int nt = 0; nt < 4; nt++)
      #pragma unroll
      for (int j = 0; j < 4; j++) {
        const int row = m0 + wm * 64 + mt * 16 + rl * 4 + j;
        const int col = n0 + wn * 64 + nt * 16 + cn;
        const size_t idx = (size_t)row * N + col;
        float v = acc[mt][nt][j];
        if (MODE == 0) {
          outb[idx] = (bf16)v;
        } else if (MODE == 1) {
          v += ld_sc(bias, col, f32);
          float gl = 0.5f * v * (1.0f + tanhf(0.7978845608028654f * (v + 0.044715f * v * v * v)));
          outb[idx] = (bf16)gl;
        } else if (MODE == 2) {
          outf[idx] = v + ld_sc(resb, idx, f32);
        } else {
          float val = v + ld_sc(bias, col, f32) + resf[idx];
          if (f32) outf[idx] = val; else outb[idx] = (bf16)val;
        }
      }
}

// ---------------- GEMM 128x64 (BK=64): for N=1024 shapes, 2x block count ----------------
template <int MODE>
__global__ __launch_bounds__(256) void gemm_bt2(const bf16* __restrict__ A,
                                                const bf16* __restrict__ BT,
                                                int N, int K,
                                                const void* __restrict__ bias,
                                                const void* __restrict__ resb,
                                                const float* __restrict__ resf,
                                                bf16* __restrict__ outb,
                                                float* __restrict__ outf,
                                                const int* __restrict__ flagp) {
  __shared__ __align__(16) bf16 sA[128 * 64];
  __shared__ __align__(16) bf16 sB[64 * 64];
  const int f32 = flagp[0];
  const int tid = threadIdx.x;
  const int lane = tid & 63;
  const int wave = tid >> 6;
  const int wm = wave >> 1, wn = wave & 1;   // wm: 2x64 rows, wn: 2x32 cols
  const int m0 = blockIdx.y * 128, n0 = blockIdx.x * 64;
  const int cn = lane & 15, rl = lane >> 4;
  const int r0 = tid >> 3, c16 = tid & 7;

  f32x4 zero = {0.f, 0.f, 0.f, 0.f};
  f32x4 acc[4][2];
  #pragma unroll
  for (int i = 0; i < 4; i++)
    #pragma unroll
    for (int j = 0; j < 2; j++) acc[i][j] = zero;

  for (int k0 = 0; k0 < K; k0 += 64) {
    __syncthreads();
    #pragma unroll
    for (int i = 0; i < 4; i++) {
      int row = r0 + i * 32;
      gll16(A + (size_t)(m0 + row) * K + k0 + c16 * 8, &sA[row * 64 + c16 * 8]);
    }
    #pragma unroll
    for (int i = 0; i < 2; i++) {
      int row = r0 + i * 32;
      gll16(BT + (size_t)(n0 + row) * K + k0 + c16 * 8, &sB[row * 64 + c16 * 8]);
    }
    __syncthreads();
    #pragma unroll
    for (int kk = 0; kk < 64; kk += 32) {
      bf16x8 af[4], bfr[2];
      #pragma unroll
      for (int t = 0; t < 4; t++)
        af[t] = *(const bf16x8*)&sA[(wm * 64 + t * 16 + cn) * 64 + kk + rl * 8];
      #pragma unroll
      for (int t = 0; t < 2; t++)
        bfr[t] = *(const bf16x8*)&sB[(wn * 32 + t * 16 + cn) * 64 + kk + rl * 8];
      #pragma unroll
      for (int mt = 0; mt < 4; mt++)
        #pragma unroll
        for (int nt = 0; nt < 2; nt++)
          acc[mt][nt] = mfma16(af[mt], bfr[nt], acc[mt][nt]);
    }
  }

  #pragma unroll
  for (int mt = 0; mt < 4; mt++)
    #pragma unroll
    for (int nt = 0; nt < 2; nt++)
      #pragma unroll
      for (int j = 0; j < 4; j++) {
        const int row = m0 + wm * 64 + mt * 16 + rl * 4 + j;
        const int col = n0 + wn * 32 + nt * 16 + cn;
        const size_t idx = (size_t)row * N + col;
        float v = acc[mt][nt][j];
        if (MODE == 0) {
          outb[idx] = (bf16)v;
        } else if (MODE == 1) {
          v += ld_sc(bias, col, f32);
          float gl = 0.5f * v * (1.0f + tanhf(0.7978845608028654f * (v + 0.044715f * v * v * v)));
          outb[idx] = (bf16)gl;
        } else if (MODE == 2) {
          outf[idx] = v + ld_sc(resb, idx, f32);
        } else {
          float val = v + ld_sc(bias, col, f32) + resf[idx];
          if (f32) outf[idx] = val; else outb[idx] = (bf16)val;
        }
      }
}

// ---------------- Attention: single pass, no-max softmax, unnormalized P ----------------
// Q tile = 128 rows; grid (S/128, H, B). Writes exp(s) to P (unnormalized),
// O (normalized) to ao, and 1/l per row to linv for the pnorm fixup.
__global__ __launch_bounds__(256) void attn_k(const bf16* __restrict__ qkv,
                                              const bf16* __restrict__ vT,
                                              void* __restrict__ Pv,
                                              bf16* __restrict__ ao,
                                              float* __restrict__ linv,
                                              const int* __restrict__ flagp) {
  __shared__ __align__(16) bf16 sQ[128 * 64];
  __shared__ __align__(16) bf16 sK[64 * 64];
  __shared__ __align__(16) bf16 sV[64 * 64];
  __shared__ __align__(16) bf16 sP[4][32 * 64];
  const int f32o = flagp[0];
  const int tid = threadIdx.x, lane = tid & 63, wave = tid >> 6;
  const int qt = blockIdx.x, h = blockIdx.y, b = blockIdx.z;
  const int cn = lane & 15, rl = lane >> 4;
  const int r0 = tid >> 3, c16 = tid & 7;
  const float C2 = 0.125f * 1.4426950408889634f;  // fold 1/sqrt(64) into exp2

  // stage Q tile [128 q][64 hd]
  #pragma unroll
  for (int i = 0; i < 4; i++) {
    int row = r0 + i * 32;
    gll16(qkv + (size_t)(b * S_ + qt * 128 + row) * 3072 + h * 64 + c16 * 8,
          &sQ[row * 64 + c16 * 8]);
  }

  f32x4 o[2][4];
  float lp[2][4];
  #pragma unroll
  for (int mt = 0; mt < 2; mt++)
    #pragma unroll
    for (int nt = 0; nt < 4; nt++) { o[mt][nt] = (f32x4){0.f, 0.f, 0.f, 0.f}; }
  #pragma unroll
  for (int mt = 0; mt < 2; mt++)
    #pragma unroll
    for (int j = 0; j < 4; j++) lp[mt][j] = 0.f;

  const int ktmax = 2 * qt + 1;
  for (int kt = 0; kt <= ktmax; kt++) {
    __syncthreads();
    #pragma unroll
    for (int i = 0; i < 2; i++) {
      int row = r0 + i * 32;
      gll16(qkv + (size_t)(b * S_ + kt * 64 + row) * 3072 + 1024 + h * 64 + c16 * 8,
            &sK[row * 64 + c16 * 8]);
      gll16(vT + ((size_t)(b * H_ + h) * 64 + row) * S_ + kt * 64 + c16 * 8,
            &sV[row * 64 + c16 * 8]);
    }
    __syncthreads();

    f32x4 s[2][4];
    #pragma unroll
    for (int mt = 0; mt < 2; mt++)
      #pragma unroll
      for (int nt = 0; nt < 4; nt++) s[mt][nt] = (f32x4){0.f, 0.f, 0.f, 0.f};
    #pragma unroll
    for (int kk = 0; kk < 64; kk += 32) {
      bf16x8 a[2], bb[4];
      #pragma unroll
      for (int mt = 0; mt < 2; mt++)
        a[mt] = *(const bf16x8*)&sQ[(wave * 32 + mt * 16 + cn) * 64 + kk + rl * 8];
      #pragma unroll
      for (int nt = 0; nt < 4; nt++)
        bb[nt] = *(const bf16x8*)&sK[(nt * 16 + cn) * 64 + kk + rl * 8];
      #pragma unroll
      for (int mt = 0; mt < 2; mt++)
        #pragma unroll
        for (int nt = 0; nt < 4; nt++)
          s[mt][nt] = mfma16(a[mt], bb[nt], s[mt][nt]);
    }

    // p = exp2(s*C2), causal mask only on the two diagonal-straddling tiles
    if (kt >= 2 * qt) {
      #pragma unroll
      for (int mt = 0; mt < 2; mt++)
        #pragma unroll
        for (int nt = 0; nt < 4; nt++)
          #pragma unroll
          for (int j = 0; j < 4; j++) {
            int rowg = qt * 128 + wave * 32 + mt * 16 + rl * 4 + j;
            int colg = kt * 64 + nt * 16 + cn;
            float p = (colg > rowg) ? 0.f : exp2f(s[mt][nt][j] * C2);
            lp[mt][j] += p;
            sP[wave][(mt * 16 + rl * 4 + j) * 64 + nt * 16 + cn] = (bf16)p;
          }
    } else {
      #pragma unroll
      for (int mt = 0; mt < 2; mt++)
        #pragma unroll
        for (int nt = 0; nt < 4; nt++)
          #pragma unroll
          for (int j = 0; j < 4; j++) {
            float p = exp2f(s[mt][nt][j] * C2);
            lp[mt][j] += p;
            sP[wave][(mt * 16 + rl * 4 + j) * 64 + nt * 16 + cn] = (bf16)p;
          }
    }
    __syncthreads();

    // O += P @ V
    #pragma unroll
    for (int kk = 0; kk < 64; kk += 32) {
      bf16x8 ap[2], bv[4];
      #pragma unroll
      for (int mt = 0; mt < 2; mt++)
        ap[mt] = *(const bf16x8*)&sP[wave][(mt * 16 + cn) * 64 + kk + rl * 8];
      #pragma unroll
      for (int nt = 0; nt < 4; nt++)
        bv[nt] = *(const bf16x8*)&sV[(nt * 16 + cn) * 64 + kk + rl * 8];
      #pragma unroll
      for (int mt = 0; mt < 2; mt++)
        #pragma unroll
        for (int nt = 0; nt < 4; nt++)
          o[mt][nt] = mfma16(ap[mt], bv[nt], o[mt][nt]);
    }

    // write unnormalized P tile from LDS (coalesced)
    #pragma unroll
    for (int i = 0; i < 4; i++) {
      int lin = i * 64 + lane;
      int r = lin >> 3, cc = lin & 7;
      size_t base = XOUT_ +
          (((size_t)(b * H_ + h) * S_) + qt * 128 + wave * 32 + r) * S_ + kt * 64 + cc * 8;
      const bf16* src = &sP[wave][r * 64 + cc * 8];
      if (f32o) {
        float4 lo, hi;
        lo.x = (float)src[0]; lo.y = (float)src[1]; lo.z = (float)src[2]; lo.w = (float)src[3];
        hi.x = (float)src[4]; hi.y = (float)src[5]; hi.z = (float)src[6]; hi.w = (float)src[7];
        *(float4*)((float*)Pv + base) = lo;
        *(float4*)((float*)Pv + base + 4) = hi;
      } else {
        *(uint4*)((bf16*)Pv + base) = *(const uint4*)src;
      }
    }
  }

  // reduce l across the 16 lanes sharing each row
  #pragma unroll
  for (int mt = 0; mt < 2; mt++)
    #pragma unroll
    for (int j = 0; j < 4; j++) {
      #pragma unroll
      for (int d = 1; d < 16; d <<= 1) lp[mt][j] += __shfl_xor(lp[mt][j], d);
      lp[mt][j] = 1.0f / lp[mt][j];
    }

  if (cn == 0) {
    #pragma unroll
    for (int mt = 0; mt < 2; mt++)
      #pragma unroll
      for (int j = 0; j < 4; j++)
        linv[((size_t)(b * H_ + h)) * S_ + qt * 128 + wave * 32 + mt * 16 + rl * 4 + j] =
            lp[mt][j];
  }

  #pragma unroll
  for (int mt = 0; mt < 2; mt++)
    #pragma unroll
    for (int nt = 0; nt < 4; nt++)
      #pragma unroll
      for (int j = 0; j < 4; j++) {
        int rowg = b * S_ + qt * 128 + wave * 32 + mt * 16 + rl * 4 + j;
        ao[(size_t)rowg * 1024 + h * 64 + nt * 16 + cn] = (bf16)(o[mt][nt][j] * lp[mt][j]);
      }
}

// ---------------- P normalize + upper-triangle zero-fill ----------------
__global__ __launch_bounds__(256) void pnorm_k(void* __restrict__ Pv,
                                               const float* __restrict__ linv,
                                               const int* __restrict__ flagp) {
  const int f32o = flagp[0];
  const int qt = blockIdx.x, h = blockIdx.y, b = blockIdx.z;
  const int tid = threadIdx.x;
  const int cc = tid * 8;
  for (int it = 0; it < 64; it++) {
    const int r = qt * 64 + it;
    const float inv = linv[((size_t)(b * H_ + h)) * S_ + r];
    const size_t base = XOUT_ + (((size_t)(b * H_ + h) * S_) + r) * S_ + cc;
    if (cc + 7 <= r) {
      if (f32o) {
        float4 a = *(float4*)((float*)Pv + base);
        float4 c = *(float4*)((float*)Pv + base + 4);
        a.x *= inv; a.y *= inv; a.z *= inv; a.w *= inv;
        c.x *= inv; c.y *= inv; c.z *= inv; c.w *= inv;
        *(float4*)((float*)Pv + base) = a;
        *(float4*)((float*)Pv + base + 4) = c;
      } else {
        uint4 u = *(uint4*)((bf16*)Pv + base);
        unsigned short* us = (unsigned short*)&u;
        #pragma unroll
        for (int e = 0; e < 8; e++) us[e] = f2bu(bfu2f(us[e]) * inv);
        *(uint4*)((bf16*)Pv + base) = u;
      }
    } else if (cc > r) {
      if (f32o) {
        float4 z = {0.f, 0.f, 0.f, 0.f};
        *(float4*)((float*)Pv + base) = z;
        *(float4*)((float*)Pv + base + 4) = z;
      } else {
        uint4 z; z.x = 0; z.y = 0; z.z = 0; z.w = 0;
        *(uint4*)((bf16*)Pv + base) = z;
      }
    } else {
      // straddles the diagonal
      if (f32o) {
        #pragma unroll
        for (int e = 0; e < 8; e++) {
          float* p = (float*)Pv + base + e;
          *p = (cc + e <= r) ? (*p) * inv : 0.f;
        }
      } else {
        #pragma unroll
        for (int e = 0; e < 8; e++) {
          bf16* p = (bf16*)Pv + base + e;
          *p = (cc + e <= r) ? (bf16)(bfu2f(*(unsigned short*)p) * inv) : (bf16)0.f;
        }
      }
    }
  }
}

extern "C" void kernel_launch(void* const* d_in, const int* in_sizes, int n_in,
                              void* d_out, int out_size, void* d_ws, size_t ws_size,
                              hipStream_t stream) {
  (void)in_sizes; (void)n_in; (void)out_size; (void)ws_size;
  const void* x    = d_in[0];
  const void* ln1g = d_in[1];
  const void* ln1b = d_in[2];
  const void* Wq   = d_in[3];
  const void* Wk   = d_in[4];
  const void* Wv   = d_in[5];
  const void* Wo   = d_in[6];
  const void* ln2g = d_in[7];
  const void* ln2b = d_in[8];
  const void* fc1w = d_in[9];
  const void* fc1b = d_in[10];
  const void* fc2w = d_in[11];
  const void* fc2b = d_in[12];

  char* ws = (char*)d_ws;
  bf16* wqkvT = (bf16*)(ws + 0);              // [3072][1024]; dead after QKV GEMM
  float* lws  = (float*)(ws + 0);             // [2*16*2048] f32 256 KB, overlays wqkvT
  bf16* woT   = (bf16*)(ws + 6291456);        // [1024][1024]
  bf16* fc1T  = (bf16*)(ws + 8388608);        // [4096][1024]
  bf16* fc2T  = (bf16*)(ws + 16777216);       // [1024][4096]
  bf16* h     = (bf16*)(ws + 25165824);       // [4096][1024]
  bf16* qkv   = (bf16*)(ws + 33554432);       // [4096][3072]
  bf16* vT    = (bf16*)(ws + 58720256);       // [2][16][64][2048]
  bf16* m1    = (bf16*)(ws + 33554432);       // [4096][4096] reuse qkv+vT after attn
  bf16* aout  = (bf16*)(ws + 67108864);       // [4096][1024]
  float* x1   = (float*)(ws + 75497472);      // [4096][1024] f32
  int* flag   = (int*)(ws + 92274688);        // 4 B

  dim3 blk(256);

  detect_k<<<1, 64, 0, stream>>>((const unsigned short*)x, flag);

  transpose_ad<<<dim3(16, 16), blk, 0, stream>>>(Wq, (unsigned short*)wqkvT, 1024, 1024, flag);
  transpose_ad<<<dim3(16, 16), blk, 0, stream>>>(Wk, (unsigned short*)(wqkvT + 1024 * 1024), 1024, 1024, flag);
  transpose_ad<<<dim3(16, 16), blk, 0, stream>>>(Wv, (unsigned short*)(wqkvT + 2 * 1024 * 1024), 1024, 1024, flag);
  transpose_ad<<<dim3(16, 16), blk, 0, stream>>>(Wo, (unsigned short*)woT, 1024, 1024, flag);
  transpose_ad<<<dim3(64, 16), blk, 0, stream>>>(fc1w, (unsigned short*)fc1T, 1024, 4096, flag);
  transpose_ad<<<dim3(16, 64), blk, 0, stream>>>(fc2w, (unsigned short*)fc2T, 4096, 1024, flag);

  ln_k<<<4096, blk, 0, stream>>>(x, ln1g, ln1b, h, flag, 0);

  gemm_bt<0><<<dim3(24, 32), blk, 0, stream>>>(h, wqkvT, 3072, 1024, nullptr, nullptr, nullptr, qkv, nullptr, flag);

  vtrans_k<<<dim3(32, 16, 2), blk, 0, stream>>>((const unsigned short*)qkv, (unsigned short*)vT);

  attn_k<<<dim3(16, 16, 2), blk, 0, stream>>>(qkv, vT, d_out, aout, lws, flag);

  pnorm_k<<<dim3(32, 16, 2), blk, 0, stream>>>(d_out, lws, flag);

  gemm_bt2<2><<<dim3(16, 32), blk, 0, stream>>>(aout, woT, 1024, 1024, nullptr, x, nullptr, nullptr, x1, flag);

  ln_k<<<4096, blk, 0, stream>>>(x1, ln2g, ln2b, h, flag, 1);

  gemm_bt<1><<<dim3(32, 32), blk, 0, stream>>>(h, fc1T, 4096, 1024, fc1b, nullptr, nullptr, m1, nullptr, flag);

  gemm_bt2<3><<<dim3(16, 32), blk, 0, stream>>>(m1, fc2T, 1024, 4096, fc2b, nullptr, x1, (bf16*)d_out, (float*)d_out, flag);
}